// Round 9
// baseline (520.293 us; speedup 1.0000x reference)
//
#include <hip/hip_runtime.h>
#include <hip/hip_bf16.h>
#include <cstdint>

#define NODES  65536
#define CH     128
#define NGRAPH 1024
#define PGRAPH 64
#define FCO    65536

typedef __bf16 bf16x8 __attribute__((ext_vector_type(8)));
typedef float  f32x4  __attribute__((ext_vector_type(4)));

// ---------------- graph preprocessing ----------------

__global__ void k_zero2(int* __restrict__ a, int* __restrict__ b){
  const int i = blockIdx.x*256 + threadIdx.x;
  ((int4*)a)[i] = make_int4(0,0,0,0);
  ((int4*)b)[i] = make_int4(0,0,0,0);
}

__global__ void k_degree(const int* __restrict__ dst, int* __restrict__ deg, int E){
  int e = blockIdx.x*256 + threadIdx.x;
  if (e < E) atomicAdd(&deg[dst[e]], 1);
}

__global__ void k_dinv(const int* __restrict__ deg, float* __restrict__ dinv){
  int i = blockIdx.x*256 + threadIdx.x;
  dinv[i] = 1.0f / sqrtf((float)(deg[i] + 1));   // self-loop -> deg+1 >= 1
}

__global__ void k_scan1(const int* __restrict__ deg, int* __restrict__ excl,
                        int* __restrict__ bsums){
  __shared__ int tmp[256];
  const int t = threadIdx.x;
  const int gid = blockIdx.x*256 + t;
  const int v = deg[gid];
  tmp[t] = v;
  __syncthreads();
  #pragma unroll
  for (int off = 1; off < 256; off <<= 1){
    int x = (t >= off) ? tmp[t-off] : 0;
    __syncthreads();
    tmp[t] += x;
    __syncthreads();
  }
  excl[gid] = tmp[t] - v;
  if (t == 255) bsums[blockIdx.x] = tmp[255];
}

__global__ void k_scan2(int* __restrict__ bsums){
  __shared__ int tmp[256];
  const int t = threadIdx.x;
  const int v = bsums[t];
  tmp[t] = v;
  __syncthreads();
  #pragma unroll
  for (int off = 1; off < 256; off <<= 1){
    int x = (t >= off) ? tmp[t-off] : 0;
    __syncthreads();
    tmp[t] += x;
    __syncthreads();
  }
  bsums[t] = tmp[t] - v;   // exclusive
}

__global__ void k_scan3(int* __restrict__ cstart, const int* __restrict__ bsums, int E){
  const int gid = blockIdx.x*256 + threadIdx.x;
  cstart[gid] += bsums[blockIdx.x];
  if (gid == 0) cstart[NODES] = E;
}

__global__ void k_scatter(const int* __restrict__ src, const int* __restrict__ dst,
                          const int* __restrict__ cstart, int* __restrict__ cursor,
                          int* __restrict__ ssrc, int E){
  int e = blockIdx.x*256 + threadIdx.x;
  if (e >= E) return;
  const int d = dst[e];
  const int p = cstart[d] + atomicAdd(&cursor[d], 1);
  ssrc[p] = src[e];
}

// ---------------- GEMM: C[n x 128] = act(A)[n x 128] @ W[128 x 128] ----------------
template<int ACT>
__global__ __launch_bounds__(256)
void k_gemm128(const float* __restrict__ A, const float* __restrict__ W,
               const float* __restrict__ bias, float* __restrict__ Cout){
  __shared__ float As[128][36];
  __shared__ float Ws[32][160];
  const int t  = threadIdx.x;
  const int r0 = blockIdx.x * 128;
  const int q  = t & 3;
  const int rp = t >> 2;

  float acc0[32], acc1[32];
  #pragma unroll
  for (int j = 0; j < 32; ++j){ acc0[j] = 0.f; acc1[j] = 0.f; }

  for (int kc = 0; kc < 128; kc += 32){
    {
      const int row = t >> 1, u = t & 1;
      const float* ap = A + (size_t)(r0+row)*CH + kc + u*16;
      float* asp = &As[row][u*16];
      #pragma unroll
      for (int i = 0; i < 4; ++i){
        float4 v = *(const float4*)(ap + 4*i);
        if (ACT){
          const float4 bb = *(const float4*)(bias + kc + u*16 + 4*i);
          v.x = fmaxf(v.x+bb.x, 0.f); v.y = fmaxf(v.y+bb.y, 0.f);
          v.z = fmaxf(v.z+bb.z, 0.f); v.w = fmaxf(v.w+bb.w, 0.f);
        }
        *(float4*)(asp + 4*i) = v;
      }
    }
    {
      const int kk = t >> 3, u = t & 7;
      const float* wp = W + (size_t)(kc+kk)*CH + u*16;
      float* wsp = &Ws[kk][(u>>1)*40 + (u&1)*16];
      #pragma unroll
      for (int i = 0; i < 4; ++i)
        *(float4*)(wsp + 4*i) = *(const float4*)(wp + 4*i);
    }
    __syncthreads();

    #pragma unroll
    for (int kk4 = 0; kk4 < 8; ++kk4){
      const float4 a0 = *(const float4*)&As[rp][kk4*4];
      const float4 a1 = *(const float4*)&As[rp+64][kk4*4];
      const float a0f[4] = {a0.x, a0.y, a0.z, a0.w};
      const float a1f[4] = {a1.x, a1.y, a1.z, a1.w};
      #pragma unroll
      for (int kk = 0; kk < 4; ++kk){
        const float av0 = a0f[kk], av1 = a1f[kk];
        #pragma unroll
        for (int j4 = 0; j4 < 8; ++j4){
          const float4 w = *(const float4*)&Ws[kk4*4+kk][q*40 + j4*4];
          acc0[j4*4+0] = fmaf(av0, w.x, acc0[j4*4+0]);
          acc0[j4*4+1] = fmaf(av0, w.y, acc0[j4*4+1]);
          acc0[j4*4+2] = fmaf(av0, w.z, acc0[j4*4+2]);
          acc0[j4*4+3] = fmaf(av0, w.w, acc0[j4*4+3]);
          acc1[j4*4+0] = fmaf(av1, w.x, acc1[j4*4+0]);
          acc1[j4*4+1] = fmaf(av1, w.y, acc1[j4*4+1]);
          acc1[j4*4+2] = fmaf(av1, w.z, acc1[j4*4+2]);
          acc1[j4*4+3] = fmaf(av1, w.w, acc1[j4*4+3]);
        }
      }
    }
    __syncthreads();
  }

  float* c0 = Cout + (size_t)(r0+rp)*CH    + q*32;
  float* c1 = Cout + (size_t)(r0+rp+64)*CH + q*32;
  #pragma unroll
  for (int j4 = 0; j4 < 8; ++j4){
    *(float4*)(c0 + j4*4) = make_float4(acc0[j4*4], acc0[j4*4+1], acc0[j4*4+2], acc0[j4*4+3]);
    *(float4*)(c1 + j4*4) = make_float4(acc1[j4*4], acc1[j4*4+1], acc1[j4*4+2], acc1[j4*4+3]);
  }
}

// ---------------- CSR aggregation: 1 wave / node, float2 / lane, 4-wide edge unroll ----
__global__ __launch_bounds__(256)
void k_agg(const float* __restrict__ hw, const float* __restrict__ dinv,
           const int* __restrict__ start, const int* __restrict__ srcs,
           float* __restrict__ outp){
  const int wave = threadIdx.x >> 6, l = threadIdx.x & 63;
  const int i = blockIdx.x*4 + wave;
  const int c = l*2;
  const float di = dinv[i];
  const float2 hself = *(const float2*)&hw[(size_t)i*CH + c];
  float ax = di * hself.x, ay = di * hself.y;

  int p = start[i];
  const int p1 = start[i+1];
  for (; p + 3 < p1; p += 4){
    const int s0 = srcs[p], s1 = srcs[p+1], s2 = srcs[p+2], s3 = srcs[p+3];
    const float w0 = dinv[s0], w1 = dinv[s1], w2 = dinv[s2], w3 = dinv[s3];
    const float2 r0 = *(const float2*)&hw[(size_t)s0*CH + c];
    const float2 r1 = *(const float2*)&hw[(size_t)s1*CH + c];
    const float2 r2 = *(const float2*)&hw[(size_t)s2*CH + c];
    const float2 r3 = *(const float2*)&hw[(size_t)s3*CH + c];
    ax += w0*r0.x; ay += w0*r0.y;
    ax += w1*r1.x; ay += w1*r1.y;
    ax += w2*r2.x; ay += w2*r2.y;
    ax += w3*r3.x; ay += w3*r3.y;
  }
  for (; p < p1; ++p){
    const int s = srcs[p];
    const float w = dinv[s];
    const float2 r = *(const float2*)&hw[(size_t)s*CH + c];
    ax += w*r.x; ay += w*r.y;
  }
  float2 o; o.x = di*ax; o.y = di*ay;
  *(float2*)&outp[(size_t)i*CH + c] = o;
}

// ---------------- pool -> split-bf16 ----------------
__global__ void k_pool(const float* __restrict__ h, const float* __restrict__ b2,
                       __bf16* __restrict__ phi, __bf16* __restrict__ plo){
  const int g = blockIdx.x, c = threadIdx.x;
  const float bb = b2[c];
  float acc = 0.f;
  const float* hp = h + (size_t)g*PGRAPH*CH + c;
  #pragma unroll 4
  for (int i = 0; i < PGRAPH; ++i) acc += fmaxf(hp[i*CH] + bb, 0.f);
  const float v = acc * (1.0f/64.0f);
  const __bf16 hv = (__bf16)v;
  phi[g*CH + c] = hv;
  plo[g*CH + c] = (__bf16)(v - (float)hv);
}

// ---------------- Wfc [128][65536] f32 -> transposed split-bf16 [65536][128] ----------------
__global__ __launch_bounds__(256)
void k_cvt_wfc(const float* __restrict__ Wfc, __bf16* __restrict__ wth,
               __bf16* __restrict__ wtl){
  __shared__ float ls[128][65];
  const int t  = threadIdx.x;
  const int c0 = blockIdx.x*64;

  #pragma unroll 8
  for (int it = 0; it < 32; ++it){
    const int row = it*4 + (t>>6);
    ls[row][t&63] = Wfc[(size_t)row*FCO + c0 + (t&63)];
  }
  __syncthreads();

  const int col = t>>2, q = t&3;
  #pragma unroll
  for (int i = 0; i < 4; ++i){
    bf16x8 h8, l8;
    #pragma unroll
    for (int j = 0; j < 8; ++j){
      const float v = ls[q*32 + i*8 + j][col];
      const __bf16 hv = (__bf16)v;
      h8[j] = hv;
      l8[j] = (__bf16)(v - (float)hv);
    }
    *(bf16x8*)(&wth[(size_t)(c0+col)*CH + q*32 + i*8]) = h8;
    *(bf16x8*)(&wtl[(size_t)(c0+col)*CH + q*32 + i*8]) = l8;
  }
}

// ---------------- FC via split-bf16 MFMA, A-resident, SWAPPED operands ----------------
// mfma(A=W-frag, B=pooled-frag): D row = output-col j, D col = graph.
// -> lane holds 4 CONSECUTIVE output cols => float4 coalesced stores (4 instr vs 16).

#define LOADB(BH, BL, ITC) do{ \
  const size_t cb_ = (size_t)(c0w + (ITC)*16 + lc)*CH + kq*8; \
  BH[0] = *(const bf16x8*)(wth + cb_);      BL[0] = *(const bf16x8*)(wtl + cb_); \
  BH[1] = *(const bf16x8*)(wth + cb_ + 32); BL[1] = *(const bf16x8*)(wtl + cb_ + 32); \
  BH[2] = *(const bf16x8*)(wth + cb_ + 64); BL[2] = *(const bf16x8*)(wtl + cb_ + 64); \
  BH[3] = *(const bf16x8*)(wth + cb_ + 96); BL[3] = *(const bf16x8*)(wtl + cb_ + 96); \
}while(0)

#define DOCOL(BH, BL, ITC) do{ \
  f32x4 q0 = {0.f,0.f,0.f,0.f}, q1 = {0.f,0.f,0.f,0.f}; \
  f32x4 q2 = {0.f,0.f,0.f,0.f}, q3 = {0.f,0.f,0.f,0.f}; \
  _Pragma("unroll") \
  for (int kk = 0; kk < 4; ++kk){ \
    q0 = __builtin_amdgcn_mfma_f32_16x16x32_bf16(BH[kk], ah[0][kk], q0, 0,0,0); \
    q1 = __builtin_amdgcn_mfma_f32_16x16x32_bf16(BH[kk], ah[1][kk], q1, 0,0,0); \
    q2 = __builtin_amdgcn_mfma_f32_16x16x32_bf16(BH[kk], ah[2][kk], q2, 0,0,0); \
    q3 = __builtin_amdgcn_mfma_f32_16x16x32_bf16(BH[kk], ah[3][kk], q3, 0,0,0); \
    q0 = __builtin_amdgcn_mfma_f32_16x16x32_bf16(BL[kk], ah[0][kk], q0, 0,0,0); \
    q1 = __builtin_amdgcn_mfma_f32_16x16x32_bf16(BL[kk], ah[1][kk], q1, 0,0,0); \
    q2 = __builtin_amdgcn_mfma_f32_16x16x32_bf16(BL[kk], ah[2][kk], q2, 0,0,0); \
    q3 = __builtin_amdgcn_mfma_f32_16x16x32_bf16(BL[kk], ah[3][kk], q3, 0,0,0); \
    q0 = __builtin_amdgcn_mfma_f32_16x16x32_bf16(BH[kk], al[0][kk], q0, 0,0,0); \
    q1 = __builtin_amdgcn_mfma_f32_16x16x32_bf16(BH[kk], al[1][kk], q1, 0,0,0); \
    q2 = __builtin_amdgcn_mfma_f32_16x16x32_bf16(BH[kk], al[2][kk], q2, 0,0,0); \
    q3 = __builtin_amdgcn_mfma_f32_16x16x32_bf16(BH[kk], al[3][kk], q3, 0,0,0); \
  } \
  const int cc = c0w + (ITC)*16 + kq*4;  /* 4 consecutive out-cols for this lane */ \
  const float4 b4 = *(const float4*)&bfc[cc]; \
  { float4 v; \
    v.x=q0[0]+b4.x; v.y=q0[1]+b4.y; v.z=q0[2]+b4.z; v.w=q0[3]+b4.w; \
    *(float4*)&out[(size_t)(g0 +  0 + lc)*FCO + cc] = v; \
    v.x=q1[0]+b4.x; v.y=q1[1]+b4.y; v.z=q1[2]+b4.z; v.w=q1[3]+b4.w; \
    *(float4*)&out[(size_t)(g0 + 16 + lc)*FCO + cc] = v; \
    v.x=q2[0]+b4.x; v.y=q2[1]+b4.y; v.z=q2[2]+b4.z; v.w=q2[3]+b4.w; \
    *(float4*)&out[(size_t)(g0 + 32 + lc)*FCO + cc] = v; \
    v.x=q3[0]+b4.x; v.y=q3[1]+b4.y; v.z=q3[2]+b4.z; v.w=q3[3]+b4.w; \
    *(float4*)&out[(size_t)(g0 + 48 + lc)*FCO + cc] = v; } \
}while(0)

__global__ __launch_bounds__(256)
void k_fc_mfma(const __bf16* __restrict__ phi, const __bf16* __restrict__ plo,
               const __bf16* __restrict__ wth, const __bf16* __restrict__ wtl,
               const float* __restrict__ bfc, float* __restrict__ out){
  const int t    = threadIdx.x;
  const int lane = t & 63, wave = t >> 6;
  const int lc   = lane & 15, kq = lane >> 4;
  const int g0   = blockIdx.y*64;
  const int c0w  = blockIdx.x*2048 + wave*512;   // wave's contiguous col range

  bf16x8 ah[4][4], al[4][4];
  #pragma unroll
  for (int gt = 0; gt < 4; ++gt){
    const __bf16* pa = phi + (size_t)(g0 + gt*16 + lc)*CH + kq*8;
    const __bf16* pb = plo + (size_t)(g0 + gt*16 + lc)*CH + kq*8;
    #pragma unroll
    for (int kk = 0; kk < 4; ++kk){
      ah[gt][kk] = *(const bf16x8*)(pa + kk*32);
      al[gt][kk] = *(const bf16x8*)(pb + kk*32);
    }
  }

  bf16x8 bhA[4], blA[4], bhB[4], blB[4];
  LOADB(bhA, blA, 0);
  #pragma unroll 1
  for (int it = 0; it < 32; it += 2){
    LOADB(bhB, blB, it+1);
    DOCOL(bhA, blA, it);
    if (it + 2 < 32) LOADB(bhA, blA, it+2);
    DOCOL(bhB, blB, it+1);
  }
}

// ---------------- launch ----------------

extern "C" void kernel_launch(void* const* d_in, const int* in_sizes, int n_in,
                              void* d_out, int out_size, void* d_ws, size_t ws_size,
                              hipStream_t stream){
  const float* x   = (const float*)d_in[0];
  const int*   ei  = (const int*)d_in[1];   // [2, E] int32 (jax x64 off)
  const float* W1  = (const float*)d_in[3];
  const float* b1  = (const float*)d_in[4];
  const float* W2  = (const float*)d_in[5];
  const float* b2  = (const float*)d_in[6];
  const float* Wfc = (const float*)d_in[7];
  const float* bfc = (const float*)d_in[8];
  float* out = (float*)d_out;
  const int E = in_sizes[1] / 2;

  float* bufA   = (float*)d_ws;                      // 33.5 MB (reused for WT hi/lo)
  float* bufB   = bufA + (size_t)NODES*CH;           // 33.5 MB
  float* dinv   = bufB + (size_t)NODES*CH;           // 256 KB
  int*   deg    = (int*)(dinv + NODES);              // 256 KB
  int*   cstart = deg + NODES;                       // NODES+1 (+256 reserve)
  int*   cursor = cstart + NODES + 256;              // 256 KB
  int*   bsums  = cursor + NODES;                    // 1 KB
  int*   ssrc   = bsums + 256;                       // 4 MB
  __bf16* phi   = (__bf16*)(ssrc + E);               // 256 KB
  __bf16* plo   = phi + (size_t)NGRAPH*CH;           // 256 KB

  __bf16* wth = (__bf16*)bufA;                       // 16.78 MB
  __bf16* wtl = wth + (size_t)FCO*CH;                // 16.78 MB

  const int* esrc = ei;
  const int* edst = ei + E;

  k_zero2  <<<NODES/1024,  256, 0, stream>>>(deg, cursor);
  k_degree <<<(E+255)/256, 256, 0, stream>>>(edst, deg, E);
  k_dinv   <<<NODES/256,   256, 0, stream>>>(deg, dinv);
  k_scan1  <<<NODES/256,   256, 0, stream>>>(deg, cstart, bsums);
  k_scan2  <<<1,           256, 0, stream>>>(bsums);
  k_scan3  <<<NODES/256,   256, 0, stream>>>(cstart, bsums, E);
  k_scatter<<<(E+255)/256, 256, 0, stream>>>(esrc, edst, cstart, cursor, ssrc, E);

  k_gemm128<0><<<NODES/128, 256, 0, stream>>>(x,    W1, nullptr, bufA);   // bufA = x@W1
  k_agg       <<<NODES/4, 256, 0, stream>>>(bufA, dinv, cstart, ssrc, bufB); // bufB = agg1
  k_gemm128<1><<<NODES/128, 256, 0, stream>>>(bufB, W2, b1,     bufA);    // bufA = relu(agg1+b1)@W2
  k_agg       <<<NODES/4, 256, 0, stream>>>(bufA, dinv, cstart, ssrc, bufB); // bufB = agg2

  // bufA dead -> transposed split-bf16 Wfc
  k_cvt_wfc <<<FCO/64, 256, 0, stream>>>(Wfc, wth, wtl);
  k_pool    <<<NGRAPH, CH, 0, stream>>>(bufB, b2, phi, plo);
  k_fc_mfma <<<dim3(32, NGRAPH/64), 256, 0, stream>>>(phi, plo, wth, wtl, bfc, out);
}